// Round 16
// baseline (284.040 us; speedup 1.0000x reference)
//
#include <hip/hip_runtime.h>

#define B_ 16
#define M_ 2048
#define NW 16              /* waves per block */
#define THREADS 1024
#define ITERS 10
#define MSE_THR 1e-5f
#define EPS_ 1e-8f

// ws layout:
//   ints   [0, 5120)        batch arrival counters, (b*ITERS+it)*CNT_STRIDE
//   ints   [5120, 8192)     pair flags, PF_OFF + (b*8+chunk)*ITERS + it
//   floats [8192, 28672)    partial rows, double-buffered by parity
//   floats [28672, 94208)   pair buffer: ((b*8+chunk)*256 + src)*2 = {val, idx}
#define CNT_STRIDE 32
#define PF_OFF 5120
#define PART_OFF 8192
#define PSTRIDE 20
#define ROWS_PER_B 32      /* 8 chunks * 4 waves */
#define PART_SZ (B_ * ROWS_PER_B * PSTRIDE)
#define PAIR_OFF 28672
#define ARRIVALS 32        /* 8 half0-blocks * 4 merge waves */

typedef float f2 __attribute__((ext_vector_type(2)));

// Kabsch update from the 17 accumulated sums (3x3 Jacobi, 6 sweeps).
__device__ inline void kabsch_from_sums(const float* S, float Rn[3][3], float tn[3]) {
  float wsum = S[0] + EPS_;
  float inv = 1.f / wsum;
  float msv[3] = {S[1]*inv, S[2]*inv, S[3]*inv};
  float mqv[3] = {S[4]*inv, S[5]*inv, S[6]*inv};
  float h[3][3];
  for (int i = 0; i < 3; ++i)
    for (int j = 0; j < 3; ++j)
      h[i][j] = S[7+i*3+j] - msv[i]*S[4+j] - S[1+i]*mqv[j] + S[0]*msv[i]*mqv[j];

  float g[3][3], V[3][3];
  for (int i = 0; i < 3; ++i)
    for (int j = 0; j < 3; ++j) {
      g[i][j] = h[0][i]*h[0][j] + h[1][i]*h[1][j] + h[2][i]*h[2][j];
      V[i][j] = (i == j) ? 1.f : 0.f;
    }
  const int PP[3] = {0, 0, 1}, QQ[3] = {1, 2, 2};
  for (int sweep = 0; sweep < 6; ++sweep) {
    for (int r = 0; r < 3; ++r) {
      int p = PP[r], q = QQ[r];
      float apq = g[p][q];
      if (fabsf(apq) > 1e-30f) {
        float tau = (g[q][q] - g[p][p]) / (2.f * apq);
        float tt = (tau >= 0.f ? 1.f : -1.f) / (fabsf(tau) + sqrtf(1.f + tau*tau));
        float c = 1.f / sqrtf(1.f + tt*tt);
        float s = tt * c;
        for (int k = 0; k < 3; ++k) {
          float gkp = g[k][p], gkq = g[k][q];
          g[k][p] = c*gkp - s*gkq;
          g[k][q] = s*gkp + c*gkq;
        }
        for (int k = 0; k < 3; ++k) {
          float gpk = g[p][k], gqk = g[q][k];
          g[p][k] = c*gpk - s*gqk;
          g[q][k] = s*gpk + c*gqk;
        }
        for (int k = 0; k < 3; ++k) {
          float vkp = V[k][p], vkq = V[k][q];
          V[k][p] = c*vkp - s*vkq;
          V[k][q] = s*vkp + c*vkq;
        }
      }
    }
  }
  float lam[3] = {g[0][0], g[1][1], g[2][2]};
  for (int i = 0; i < 2; ++i)
    for (int j = i+1; j < 3; ++j)
      if (lam[i] < lam[j]) {
        float tl = lam[i]; lam[i] = lam[j]; lam[j] = tl;
        for (int k = 0; k < 3; ++k) { float tv = V[k][i]; V[k][i] = V[k][j]; V[k][j] = tv; }
      }
  float U[3][3];
  for (int k = 0; k < 3; ++k) {
    float ux = h[0][0]*V[0][k] + h[0][1]*V[1][k] + h[0][2]*V[2][k];
    float uy = h[1][0]*V[0][k] + h[1][1]*V[1][k] + h[1][2]*V[2][k];
    float uz = h[2][0]*V[0][k] + h[2][1]*V[1][k] + h[2][2]*V[2][k];
    float invs = 1.f / fmaxf(sqrtf(fmaxf(lam[k], 0.f)), 1e-20f);
    U[0][k] = ux*invs; U[1][k] = uy*invs; U[2][k] = uz*invs;
  }
  float detH = h[0][0]*(h[1][1]*h[2][2] - h[1][2]*h[2][1])
             - h[0][1]*(h[1][0]*h[2][2] - h[1][2]*h[2][0])
             + h[0][2]*(h[1][0]*h[2][1] - h[1][1]*h[2][0]);
  float d3 = (detH >= 0.f) ? 1.f : -1.f;
  for (int i = 0; i < 3; ++i)
    for (int j = 0; j < 3; ++j)
      Rn[i][j] = V[i][0]*U[j][0] + V[i][1]*U[j][1] + d3*V[i][2]*U[j][2];
  for (int i = 0; i < 3; ++i)
    tn[i] = mqv[i] - (Rn[i][0]*msv[0] + Rn[i][1]*msv[1] + Rn[i][2]*msv[2]);
}

// Zero the counter + pair-flag region (poisoned workspace).
__global__ void icp_init(unsigned* __restrict__ cnt) {
  int i = blockIdx.x * blockDim.x + threadIdx.x;
  if (i < PART_OFF) cnt[i] = 0u;
}

// Fused persistent ICP. grid = 256 blocks (1/CU) x 1024 thr (16 waves).
// SPLIT-DEST partition: sub = chunk*2 + half. Block owns 256 src
// (4/thread) x 1024 dests (64/wave) -> LDS broadcast reads per CU HALVED
// (1024 vs 2048) at identical VALU. Cross-half argmin combine via a pair
// rendezvous (half0 idx < half1 idx -> strict < keeps first occurrence).
// Tail (32 rows, batch barrier, wave0 Kabsch) identical to R14.
__global__ __launch_bounds__(THREADS, 2) void icp_fused(const float* __restrict__ src,
                                                        const float* __restrict__ dest,
                                                        float* __restrict__ ws,
                                                        float* __restrict__ out) {
  unsigned* cnt = (unsigned*)ws;
  float* partial = ws + PART_OFF;
  float* pairbuf = ws + PAIR_OFF;

  int blk = blockIdx.x;
  int b = blk >> 4, sub = blk & 15;
  int chunk = sub >> 1, half = sub & 1;
  int tid = threadIdx.x;
  int lane = tid & 63, w = tid >> 6;

  __shared__ float4 dt[M_];
  __shared__ float mval[NW][4][64];
  __shared__ int   midx[NW][4][64];
  __shared__ float Rsh[13];   // 9 R + 3 t + new_mse

  // ---- one-time staging: ALL 2048 dests {x,y,z,0.5|d|^2} into LDS ----
#pragma unroll
  for (int k = 0; k < 2; ++k) {
    int n = tid + THREADS*k;
    float dx = dest[(b*3+0)*M_ + n];
    float dy = dest[(b*3+1)*M_ + n];
    float dz = dest[(b*3+2)*M_ + n];
    dt[n] = make_float4(dx, dy, dz, 0.5f*(dx*dx + dy*dy + dz*dz));
  }
  // ---- one-time src loads (4 points per thread; same set across waves) ----
  float sxr[4], syr[4], szr[4];
#pragma unroll
  for (int g = 0; g < 4; ++g) {
    int m = chunk*256 + g*64 + lane;
    sxr[g] = src[(b*3+0)*M_ + m];
    syr[g] = src[(b*3+1)*M_ + m];
    szr[g] = src[(b*3+2)*M_ + m];
  }
  __syncthreads();

  float Rc[3][3] = {{1.f,0.f,0.f},{0.f,1.f,0.f},{0.f,0.f,1.f}};
  float tc[3] = {0.f, 0.f, 0.f};
  float mse = 0.f;
  bool done = false;

  // wave-uniform 64-dest segment base (global dest index space)
  const int sj0 = half*1024 + __builtin_amdgcn_readfirstlane(w) * 64;

  for (int it = 0; it < ITERS; ++it) {
    if (!done) {   // batch-uniform: all blocks of batch b agree bitwise
      // ---- project 4 src with current R,t ----
      float npx_[4], npy_[4], npz_[4], psq_[4];
#pragma unroll
      for (int g = 0; g < 4; ++g) {
        float sx = sxr[g], sy = syr[g], sz = szr[g];
        float px = fmaf(Rc[0][0], sx, fmaf(Rc[0][1], sy, fmaf(Rc[0][2], sz, tc[0])));
        float py = fmaf(Rc[1][0], sx, fmaf(Rc[1][1], sy, fmaf(Rc[1][2], sz, tc[1])));
        float pz = fmaf(Rc[2][0], sx, fmaf(Rc[2][1], sy, fmaf(Rc[2][2], sz, tc[2])));
        npx_[g] = -px; npy_[g] = -py; npz_[g] = -pz;
        psq_[g] = px*px + py*py + pz*pz;
      }
      f2 npxA = {npx_[0], npx_[1]}, npxB = {npx_[2], npx_[3]};
      f2 npyA = {npy_[0], npy_[1]}, npyB = {npy_[2], npy_[3]};
      f2 npzA = {npz_[0], npz_[1]}, npzB = {npz_[2], npz_[3]};

      // ---- NN scan over 64 dests: f2 packed, 2-bank 16-dest pipeline ----
      float bv0[4], bv1[4], bv2[4], bv3[4];
      int bix0[4], bix1[4], bix2[4], bix3[4];
#pragma unroll
      for (int u = 0; u < 4; ++u) {
        bv0[u] = bv1[u] = bv2[u] = bv3[u] = 3.0e38f;
        bix0[u] = bix1[u] = bix2[u] = bix3[u] = 0;
      }

#define NNS(D, IDX, U) do {                                                      \
        f2 vx = {(D).x, (D).x}, vy = {(D).y, (D).y};                             \
        f2 vz = {(D).z, (D).z}, vw = {(D).w, (D).w};                             \
        f2 aa = __builtin_elementwise_fma(npzA, vz,                              \
                 __builtin_elementwise_fma(npyA, vy,                             \
                  __builtin_elementwise_fma(npxA, vx, vw)));                     \
        f2 ab = __builtin_elementwise_fma(npzB, vz,                              \
                 __builtin_elementwise_fma(npyB, vy,                             \
                  __builtin_elementwise_fma(npxB, vx, vw)));                     \
        bool l0 = aa.x < bv0[U];                                                 \
        bv0[U] = l0 ? aa.x : bv0[U]; bix0[U] = l0 ? (IDX) : bix0[U];             \
        bool l1 = aa.y < bv1[U];                                                 \
        bv1[U] = l1 ? aa.y : bv1[U]; bix1[U] = l1 ? (IDX) : bix1[U];             \
        bool l2 = ab.x < bv2[U];                                                 \
        bv2[U] = l2 ? ab.x : bv2[U]; bix2[U] = l2 ? (IDX) : bix2[U];             \
        bool l3 = ab.y < bv3[U];                                                 \
        bv3[U] = l3 ? ab.y : bv3[U]; bix3[U] = l3 ? (IDX) : bix3[U];             \
      } while (0)

      float4 A0=dt[sj0+0],  A1=dt[sj0+1],  A2=dt[sj0+2],  A3=dt[sj0+3];
      float4 A4=dt[sj0+4],  A5=dt[sj0+5],  A6=dt[sj0+6],  A7=dt[sj0+7];
      float4 B0=dt[sj0+8],  B1=dt[sj0+9],  B2=dt[sj0+10], B3=dt[sj0+11];
      float4 B4=dt[sj0+12], B5=dt[sj0+13], B6=dt[sj0+14], B7=dt[sj0+15];

      for (int j = 0; j < 64; j += 16) {
        const int jp = (j + 16) & 63;                // wraps on last iter (harmless reload)
        NNS(A0, sj0+j+0, 0);  NNS(A1, sj0+j+1, 1);
        NNS(A2, sj0+j+2, 2);  NNS(A3, sj0+j+3, 3);
        NNS(A4, sj0+j+4, 0);  NNS(A5, sj0+j+5, 1);
        NNS(A6, sj0+j+6, 2);  NNS(A7, sj0+j+7, 3);
        A0=dt[sj0+jp+0]; A1=dt[sj0+jp+1]; A2=dt[sj0+jp+2]; A3=dt[sj0+jp+3];
        A4=dt[sj0+jp+4]; A5=dt[sj0+jp+5]; A6=dt[sj0+jp+6]; A7=dt[sj0+jp+7];
        NNS(B0, sj0+j+8,  0); NNS(B1, sj0+j+9,  1);
        NNS(B2, sj0+j+10, 2); NNS(B3, sj0+j+11, 3);
        NNS(B4, sj0+j+12, 0); NNS(B5, sj0+j+13, 1);
        NNS(B6, sj0+j+14, 2); NNS(B7, sj0+j+15, 3);
        B0=dt[sj0+jp+8];  B1=dt[sj0+jp+9];  B2=dt[sj0+jp+10]; B3=dt[sj0+jp+11];
        B4=dt[sj0+jp+12]; B5=dt[sj0+jp+13]; B6=dt[sj0+jp+14]; B7=dt[sj0+jp+15];
      }
#undef NNS

      // lexicographic residue merge (first-occurrence argmin), per src g
#define RESMERGE(BV, BIX, G) do {                                                \
        float v = BV[0]; int ix = BIX[0];                                        \
        _Pragma("unroll")                                                        \
        for (int u = 1; u < 4; ++u) {                                            \
          bool better = (BV[u] < v) || (BV[u] == v && BIX[u] < ix);              \
          v = better ? BV[u] : v;                                                \
          ix = better ? BIX[u] : ix;                                             \
        }                                                                        \
        mval[w][G][lane] = v; midx[w][G][lane] = ix;                             \
      } while (0)
      RESMERGE(bv0, bix0, 0);
      RESMERGE(bv1, bix1, 1);
      RESMERGE(bv2, bix2, 2);
      RESMERGE(bv3, bix3, 3);
#undef RESMERGE
      __syncthreads();

      unsigned* bcnt  = cnt + (b * ITERS + it) * CNT_STRIDE;
      unsigned* pflag = cnt + PF_OFF + (b*8 + chunk) * ITERS + it;

      // ---- phase 1.5: waves 0-3 merge 16 segments -> per-src half-min ----
      float v0 = 0.f; int ix0 = 0;
      if (w < 4) {
        const int g = w;
        v0 = mval[0][g][lane]; ix0 = midx[0][g][lane];
#pragma unroll
        for (int c = 1; c < NW; ++c) {       // ascending segments: strict < keeps first
          float v2 = mval[c][g][lane]; int i2 = midx[c][g][lane];
          bool lt = v2 < v0;
          v0 = lt ? v2 : v0;
          ix0 = lt ? i2 : ix0;
        }
        if (half) {                          // publish to pair partner
          float* pb = pairbuf + ((b*8 + chunk)*256 + g*64 + lane)*2;
          __hip_atomic_store(pb, v0, __ATOMIC_RELAXED, __HIP_MEMORY_SCOPE_AGENT);
          __hip_atomic_store((unsigned*)(pb+1), (unsigned)ix0,
                             __ATOMIC_RELAXED, __HIP_MEMORY_SCOPE_AGENT);
        }
        asm volatile("s_waitcnt vmcnt(0)" ::: "memory");
      }
      __syncthreads();

      if (half) {
        if (tid == 0)
          __hip_atomic_fetch_add(pflag, 1u, __ATOMIC_RELAXED, __HIP_MEMORY_SCOPE_AGENT);
      } else {
        // ---- phase 2: half0 combines, accumulates, writes 4 rows ----
        if (tid == 0) {
          while (__hip_atomic_load(pflag, __ATOMIC_RELAXED, __HIP_MEMORY_SCOPE_AGENT) < 1u)
            __builtin_amdgcn_s_sleep(1);
        }
        __syncthreads();
        if (w < 4) {
          const int g = w;
          const float* pb = pairbuf + ((b*8 + chunk)*256 + g*64 + lane)*2;
          float v1 = __hip_atomic_load(pb, __ATOMIC_RELAXED, __HIP_MEMORY_SCOPE_AGENT);
          int ix1 = (int)__hip_atomic_load((const unsigned*)(pb+1),
                                           __ATOMIC_RELAXED, __HIP_MEMORY_SCOPE_AGENT);
          bool bt = v1 < v0;                 // half1 idx > half0 idx: strict < keeps first
          float v = bt ? v1 : v0;
          int ix = bt ? ix1 : ix0;
          float psqg = (w==0) ? psq_[0] : (w==1) ? psq_[1] : (w==2) ? psq_[2] : psq_[3];
          float sxg  = (w==0) ? sxr[0]  : (w==1) ? sxr[1]  : (w==2) ? sxr[2]  : sxr[3];
          float syg  = (w==0) ? syr[0]  : (w==1) ? syr[1]  : (w==2) ? syr[2]  : syr[3];
          float szg  = (w==0) ? szr[0]  : (w==1) ? szr[1]  : (w==2) ? szr[2]  : szr[3];
          float nn = fmaxf(fmaf(2.f, v, psqg), 0.f);
          float a[17];
#pragma unroll
          for (int i = 0; i < 16; ++i) a[i] = 0.f;
          a[16] = nn;
          if (nn < 9.f) {                    // sqrt(nn) < CORR_THRESHOLD
            float4 qd = dt[ix];
            a[0] = 1.f;
            a[1] = sxg; a[2] = syg; a[3] = szg;
            a[4] = qd.x; a[5] = qd.y; a[6] = qd.z;
            a[7]  = sxg*qd.x; a[8]  = sxg*qd.y; a[9]  = sxg*qd.z;
            a[10] = syg*qd.x; a[11] = syg*qd.y; a[12] = syg*qd.z;
            a[13] = szg*qd.x; a[14] = szg*qd.y; a[15] = szg*qd.z;
          }
#pragma unroll
          for (int i = 0; i < 17; ++i) {
            float vv = a[i];
            for (int off = 32; off > 0; off >>= 1) vv += __shfl_down(vv, off);
            a[i] = vv;
          }
          if (lane == 0) {
            float* pp = partial + (it & 1) * PART_SZ
                      + (b*ROWS_PER_B + chunk*4 + g) * PSTRIDE;
#pragma unroll
            for (int i = 0; i < 17; ++i)
              __hip_atomic_store(pp + i, a[i], __ATOMIC_RELAXED, __HIP_MEMORY_SCOPE_AGENT);
          }
          asm volatile("s_waitcnt vmcnt(0)" ::: "memory");
          if (lane == 0)
            __hip_atomic_fetch_add(bcnt, 1u, __ATOMIC_RELAXED, __HIP_MEMORY_SCOPE_AGENT);
        }
      }

      // ---- batch barrier + reduce + Kabsch (wave 0 of every block) ----
      if (w == 0) {
        if (lane == 0) {
          while (__hip_atomic_load(bcnt, __ATOMIC_RELAXED, __HIP_MEMORY_SCOPE_AGENT)
                 < (unsigned)ARRIVALS)
            __builtin_amdgcn_s_sleep(1);
        }
        float vbuf[ROWS_PER_B];
        if (lane < 17) {
          const float* pp = partial + (it & 1) * PART_SZ;
#pragma unroll
          for (int c = 0; c < ROWS_PER_B; ++c)
            vbuf[c] = __hip_atomic_load(pp + (b*ROWS_PER_B + c)*PSTRIDE + lane,
                                        __ATOMIC_RELAXED, __HIP_MEMORY_SCOPE_AGENT);
        } else {
#pragma unroll
          for (int c = 0; c < ROWS_PER_B; ++c) vbuf[c] = 0.f;
        }
        float s = 0.f;
#pragma unroll
        for (int c = 0; c < ROWS_PER_B; ++c) s += vbuf[c];
        float S[17];
#pragma unroll
        for (int i = 0; i < 17; ++i) S[i] = __shfl(s, i);
        float Rn[3][3], tn[3];
        kabsch_from_sums(S, Rn, tn);
        if (lane == 0) {
          for (int i = 0; i < 3; ++i)
            for (int j = 0; j < 3; ++j) Rsh[i*3+j] = Rn[i][j];
          for (int i = 0; i < 3; ++i) Rsh[9+i] = tn[i];
          Rsh[12] = S[16] * (1.f / (float)M_);
        }
      }
      __syncthreads();
      // ---- all threads pick up the update ----
#pragma unroll
      for (int i = 0; i < 3; ++i) {
#pragma unroll
        for (int j = 0; j < 3; ++j) Rc[i][j] = Rsh[i*3+j];
        tc[i] = Rsh[9+i];
      }
      mse = Rsh[12];
      if (mse < MSE_THR) done = true;
      // LDS reuse next iteration ordered by the barriers above
    }
  }

  // ---- emit outputs (one writer per batch) ----
  if (sub == 0 && tid == 0) {
#pragma unroll
    for (int i = 0; i < 3; ++i)
#pragma unroll
      for (int j = 0; j < 3; ++j) out[b*9 + i*3 + j] = Rc[i][j];
#pragma unroll
    for (int i = 0; i < 3; ++i) out[144 + b*3 + i] = tc[i];
    out[192 + b] = mse;
  }
}

extern "C" void kernel_launch(void* const* d_in, const int* in_sizes, int n_in,
                              void* d_out, int out_size, void* d_ws, size_t ws_size,
                              hipStream_t stream) {
  const float* src  = (const float*)d_in[0];
  const float* dest = (const float*)d_in[1];
  float* out = (float*)d_out;
  float* ws = (float*)d_ws;

  // zero the (poisoned) counter + pair-flag region first
  hipLaunchKernelGGL(icp_init, dim3((PART_OFF + 255)/256), dim3(256), 0,
                     stream, (unsigned*)ws);

  // REGULAR launch: 256 blocks x 1024 thr = 50% of device thread capacity,
  // 1 block/CU (LDS ~65 KB) -> all blocks co-resident; arrival barriers safe.
  hipLaunchKernelGGL(icp_fused, dim3(256), dim3(THREADS), 0, stream,
                     src, dest, ws, out);
}

// Round 17
// 265.627 us; speedup vs baseline: 1.0693x; 1.0693x over previous
//
#include <hip/hip_runtime.h>

#define B_ 16
#define M_ 2048
#define NBLK_PER_B 16      /* blocks per batch */
#define NW 16              /* waves per block = dest segments of 128 */
#define THREADS 1024
#define ITERS 10
#define MSE_THR 1e-5f
#define EPS_ 1e-8f

// ws layout (4-byte units):
//   [0, B_*ITERS*CNT_STRIDE)        arrival counters, one slot per (b,it)
//   [PART_OFF, PART_OFF+2*PART_SZ)  partial sums, double-buffered by parity
#define CNT_STRIDE 32
#define PART_OFF 8192
#define PSTRIDE 20
#define ROWS_PER_B 32      /* 2 rows per block * 16 blocks */
#define PART_SZ (B_ * ROWS_PER_B * PSTRIDE)
#define ARRIVALS (2 * NBLK_PER_B)   /* 2 merge waves per block arrive */

typedef float f2 __attribute__((ext_vector_type(2)));

// Kabsch update from the 17 accumulated sums (3x3 Jacobi, 6 sweeps).
__device__ inline void kabsch_from_sums(const float* S, float Rn[3][3], float tn[3]) {
  float wsum = S[0] + EPS_;
  float inv = 1.f / wsum;
  float msv[3] = {S[1]*inv, S[2]*inv, S[3]*inv};
  float mqv[3] = {S[4]*inv, S[5]*inv, S[6]*inv};
  float h[3][3];
  for (int i = 0; i < 3; ++i)
    for (int j = 0; j < 3; ++j)
      h[i][j] = S[7+i*3+j] - msv[i]*S[4+j] - S[1+i]*mqv[j] + S[0]*msv[i]*mqv[j];

  float g[3][3], V[3][3];
  for (int i = 0; i < 3; ++i)
    for (int j = 0; j < 3; ++j) {
      g[i][j] = h[0][i]*h[0][j] + h[1][i]*h[1][j] + h[2][i]*h[2][j];
      V[i][j] = (i == j) ? 1.f : 0.f;
    }
  const int PP[3] = {0, 0, 1}, QQ[3] = {1, 2, 2};
  for (int sweep = 0; sweep < 6; ++sweep) {
    for (int r = 0; r < 3; ++r) {
      int p = PP[r], q = QQ[r];
      float apq = g[p][q];
      if (fabsf(apq) > 1e-30f) {
        float tau = (g[q][q] - g[p][p]) / (2.f * apq);
        float tt = (tau >= 0.f ? 1.f : -1.f) / (fabsf(tau) + sqrtf(1.f + tau*tau));
        float c = 1.f / sqrtf(1.f + tt*tt);
        float s = tt * c;
        for (int k = 0; k < 3; ++k) {
          float gkp = g[k][p], gkq = g[k][q];
          g[k][p] = c*gkp - s*gkq;
          g[k][q] = s*gkp + c*gkq;
        }
        for (int k = 0; k < 3; ++k) {
          float gpk = g[p][k], gqk = g[q][k];
          g[p][k] = c*gpk - s*gqk;
          g[q][k] = s*gpk + c*gqk;
        }
        for (int k = 0; k < 3; ++k) {
          float vkp = V[k][p], vkq = V[k][q];
          V[k][p] = c*vkp - s*vkq;
          V[k][q] = s*vkp + c*vkq;
        }
      }
    }
  }
  float lam[3] = {g[0][0], g[1][1], g[2][2]};
  for (int i = 0; i < 2; ++i)
    for (int j = i+1; j < 3; ++j)
      if (lam[i] < lam[j]) {
        float tl = lam[i]; lam[i] = lam[j]; lam[j] = tl;
        for (int k = 0; k < 3; ++k) { float tv = V[k][i]; V[k][i] = V[k][j]; V[k][j] = tv; }
      }
  float U[3][3];
  for (int k = 0; k < 3; ++k) {
    float ux = h[0][0]*V[0][k] + h[0][1]*V[1][k] + h[0][2]*V[2][k];
    float uy = h[1][0]*V[0][k] + h[1][1]*V[1][k] + h[1][2]*V[2][k];
    float uz = h[2][0]*V[0][k] + h[2][1]*V[1][k] + h[2][2]*V[2][k];
    float invs = 1.f / fmaxf(sqrtf(fmaxf(lam[k], 0.f)), 1e-20f);
    U[0][k] = ux*invs; U[1][k] = uy*invs; U[2][k] = uz*invs;
  }
  float detH = h[0][0]*(h[1][1]*h[2][2] - h[1][2]*h[2][1])
             - h[0][1]*(h[1][0]*h[2][2] - h[1][2]*h[2][0])
             + h[0][2]*(h[1][0]*h[2][1] - h[1][1]*h[2][0]);
  float d3 = (detH >= 0.f) ? 1.f : -1.f;
  for (int i = 0; i < 3; ++i)
    for (int j = 0; j < 3; ++j)
      Rn[i][j] = V[i][0]*U[j][0] + V[i][1]*U[j][1] + d3*V[i][2]*U[j][2];
  for (int i = 0; i < 3; ++i)
    tn[i] = mqv[i] - (Rn[i][0]*msv[0] + Rn[i][1]*msv[1] + Rn[i][2]*msv[2]);
}

// Zero the arrival counters (poisoned workspace -> must init before use).
__global__ void icp_init(unsigned* __restrict__ cnt) {
  int i = blockIdx.x * blockDim.x + threadIdx.x;
  if (i < B_ * ITERS * CNT_STRIDE) cnt[i] = 0u;
}

// Fused persistent ICP. grid = 256 blocks (1/CU) x 1024 thr (16 waves, 4/SIMD).
// R10 scan (packed f2 fma, 2-bank pipelined 16-dest unroll, 128-dest segments);
// fence-free per-batch barrier; parallel-issue reduce; regular launch.
__global__ __launch_bounds__(THREADS, 2) void icp_fused(const float* __restrict__ src,
                                                        const float* __restrict__ dest,
                                                        float* __restrict__ ws,
                                                        float* __restrict__ out) {
  unsigned* cnt = (unsigned*)ws;
  float* partial = ws + PART_OFF;   // 2 * PART_SZ floats

  int blk = blockIdx.x;
  int b = blk >> 4, sub = blk & 15;
  int tid = threadIdx.x;
  int lane = tid & 63, w = tid >> 6;

  __shared__ float4 dt[M_];
  __shared__ float mval[NW][2][64];
  __shared__ int   midx[NW][2][64];
  __shared__ float Rsh[13];   // 9 R + 3 t + new_mse

  // ---- one-time staging: dest tile {x,y,z,0.5|d|^2} into LDS ----
#pragma unroll
  for (int k = 0; k < 2; ++k) {
    int n = tid + THREADS*k;
    float dx = dest[(b*3+0)*M_ + n];
    float dy = dest[(b*3+1)*M_ + n];
    float dz = dest[(b*3+2)*M_ + n];
    dt[n] = make_float4(dx, dy, dz, 0.5f*(dx*dx + dy*dy + dz*dz));
  }
  // ---- one-time src loads (2 points per thread; same pts across waves) ----
  float sxr[2], syr[2], szr[2];
#pragma unroll
  for (int g = 0; g < 2; ++g) {
    int m = sub*128 + g*64 + lane;
    sxr[g] = src[(b*3+0)*M_ + m];
    syr[g] = src[(b*3+1)*M_ + m];
    szr[g] = src[(b*3+2)*M_ + m];
  }
  __syncthreads();

  float Rc[3][3] = {{1.f,0.f,0.f},{0.f,1.f,0.f},{0.f,0.f,1.f}};
  float tc[3] = {0.f, 0.f, 0.f};
  float mse = 0.f;
  bool done = false;

  const int sj0 = __builtin_amdgcn_readfirstlane(w) * 128;   // wave-uniform

  for (int it = 0; it < ITERS; ++it) {
    if (!done) {   // batch-uniform: all blocks of batch b agree bitwise
      // ---- project src with current R,t ----
      float npx[2], npy[2], npz[2];
      float psq0, psq1;
#pragma unroll
      for (int g = 0; g < 2; ++g) {
        float sx = sxr[g], sy = syr[g], sz = szr[g];
        float px = fmaf(Rc[0][0], sx, fmaf(Rc[0][1], sy, fmaf(Rc[0][2], sz, tc[0])));
        float py = fmaf(Rc[1][0], sx, fmaf(Rc[1][1], sy, fmaf(Rc[1][2], sz, tc[1])));
        float pz = fmaf(Rc[2][0], sx, fmaf(Rc[2][1], sy, fmaf(Rc[2][2], sz, tc[2])));
        npx[g] = -px; npy[g] = -py; npz[g] = -pz;
        float pq = px*px + py*py + pz*pz;
        if (g == 0) psq0 = pq; else psq1 = pq;
      }
      f2 npx2 = {npx[0], npx[1]};
      f2 npy2 = {npy[0], npy[1]};
      f2 npz2 = {npz[0], npz[1]};

      // ---- NN scan: packed fp32, 2-bank pipeline, residue chains u = idx%4 ----
      float bv0[4], bv1[4]; int bix0[4], bix1[4];
#pragma unroll
      for (int u = 0; u < 4; ++u) {
        bv0[u] = 3.0e38f; bv1[u] = 3.0e38f; bix0[u] = 0; bix1[u] = 0;
      }

#define NNS(D, IDX, U) do {                                                      \
        f2 vx = {(D).x, (D).x}, vy = {(D).y, (D).y};                             \
        f2 vz = {(D).z, (D).z}, vw = {(D).w, (D).w};                             \
        f2 aa = __builtin_elementwise_fma(npz2, vz,                              \
                 __builtin_elementwise_fma(npy2, vy,                             \
                  __builtin_elementwise_fma(npx2, vx, vw)));                     \
        bool l0 = aa.x < bv0[U];                                                 \
        bv0[U] = l0 ? aa.x : bv0[U]; bix0[U] = l0 ? (IDX) : bix0[U];             \
        bool l1 = aa.y < bv1[U];                                                 \
        bv1[U] = l1 ? aa.y : bv1[U]; bix1[U] = l1 ? (IDX) : bix1[U];             \
      } while (0)

      float4 A0=dt[sj0+0],  A1=dt[sj0+1],  A2=dt[sj0+2],  A3=dt[sj0+3];
      float4 A4=dt[sj0+4],  A5=dt[sj0+5],  A6=dt[sj0+6],  A7=dt[sj0+7];
      float4 B0=dt[sj0+8],  B1=dt[sj0+9],  B2=dt[sj0+10], B3=dt[sj0+11];
      float4 B4=dt[sj0+12], B5=dt[sj0+13], B6=dt[sj0+14], B7=dt[sj0+15];

      for (int j = 0; j < 128; j += 16) {
        const int jp = (j + 16) & 127;               // wraps on last iter (harmless reload)
        NNS(A0, sj0+j+0, 0);  NNS(A1, sj0+j+1, 1);
        NNS(A2, sj0+j+2, 2);  NNS(A3, sj0+j+3, 3);
        NNS(A4, sj0+j+4, 0);  NNS(A5, sj0+j+5, 1);
        NNS(A6, sj0+j+6, 2);  NNS(A7, sj0+j+7, 3);
        A0=dt[sj0+jp+0]; A1=dt[sj0+jp+1]; A2=dt[sj0+jp+2]; A3=dt[sj0+jp+3];
        A4=dt[sj0+jp+4]; A5=dt[sj0+jp+5]; A6=dt[sj0+jp+6]; A7=dt[sj0+jp+7];
        NNS(B0, sj0+j+8,  0); NNS(B1, sj0+j+9,  1);
        NNS(B2, sj0+j+10, 2); NNS(B3, sj0+j+11, 3);
        NNS(B4, sj0+j+12, 0); NNS(B5, sj0+j+13, 1);
        NNS(B6, sj0+j+14, 2); NNS(B7, sj0+j+15, 3);
        B0=dt[sj0+jp+8];  B1=dt[sj0+jp+9];  B2=dt[sj0+jp+10]; B3=dt[sj0+jp+11];
        B4=dt[sj0+jp+12]; B5=dt[sj0+jp+13]; B6=dt[sj0+jp+14]; B7=dt[sj0+jp+15];
      }
#undef NNS

      // lexicographic residue merge (first-occurrence argmin), per g
      {
        float v = bv0[0]; int ix = bix0[0];
#pragma unroll
        for (int u = 1; u < 4; ++u) {
          bool better = (bv0[u] < v) || (bv0[u] == v && bix0[u] < ix);
          v = better ? bv0[u] : v;
          ix = better ? bix0[u] : ix;
        }
        mval[w][0][lane] = v; midx[w][0][lane] = ix;
      }
      {
        float v = bv1[0]; int ix = bix1[0];
#pragma unroll
        for (int u = 1; u < 4; ++u) {
          bool better = (bv1[u] < v) || (bv1[u] == v && bix1[u] < ix);
          v = better ? bv1[u] : v;
          ix = better ? bix1[u] : ix;
        }
        mval[w][1][lane] = v; midx[w][1][lane] = ix;
      }
      __syncthreads();

      unsigned* cptr = cnt + (b * ITERS + it) * CNT_STRIDE;

      // ---- final merge + accumulation: wave g handles src half g (g=0,1);
      //      each merge wave self-arrives at the batch barrier ----
      if (w < 2) {
        float v = mval[0][w][lane]; int ix = midx[0][w][lane];
#pragma unroll
        for (int c = 1; c < NW; ++c) {       // ascending segments: strict < keeps first
          float v2 = mval[c][w][lane]; int i2 = midx[c][w][lane];
          bool lt = v2 < v;
          v = lt ? v2 : v;
          ix = lt ? i2 : ix;
        }
        float psqg = (w == 0) ? psq0 : psq1;
        float sxg = (w == 0) ? sxr[0] : sxr[1];
        float syg = (w == 0) ? syr[0] : syr[1];
        float szg = (w == 0) ? szr[0] : szr[1];
        float nn = fmaxf(fmaf(2.f, v, psqg), 0.f);
        float a[17];
#pragma unroll
        for (int i = 0; i < 16; ++i) a[i] = 0.f;
        a[16] = nn;
        if (nn < 9.f) {                      // sqrt(nn) < CORR_THRESHOLD
          float4 qd = dt[ix];
          a[0] = 1.f;
          a[1] = sxg; a[2] = syg; a[3] = szg;
          a[4] = qd.x; a[5] = qd.y; a[6] = qd.z;
          a[7]  = sxg*qd.x; a[8]  = sxg*qd.y; a[9]  = sxg*qd.z;
          a[10] = syg*qd.x; a[11] = syg*qd.y; a[12] = syg*qd.z;
          a[13] = szg*qd.x; a[14] = szg*qd.y; a[15] = szg*qd.z;
        }
#pragma unroll
        for (int i = 0; i < 17; ++i) {
          float vv = a[i];
          for (int off = 32; off > 0; off >>= 1) vv += __shfl_down(vv, off);
          a[i] = vv;
        }
        if (lane == 0) {
          // cache-bypassing stores straight to the coherence point
          float* pp = partial + (it & 1) * PART_SZ
                    + (b*ROWS_PER_B + sub*2 + w) * PSTRIDE;
#pragma unroll
          for (int i = 0; i < 17; ++i)
            __hip_atomic_store(pp + i, a[i], __ATOMIC_RELAXED, __HIP_MEMORY_SCOPE_AGENT);
        }
        // order by COMPLETION (per-wave), not by a cache-flushing fence
        asm volatile("s_waitcnt vmcnt(0)" ::: "memory");
        if (lane == 0)
          __hip_atomic_fetch_add(cptr, 1u, __ATOMIC_RELAXED, __HIP_MEMORY_SCOPE_AGENT);
      }

      // ---- wave 0 spins, reduces partials, runs Kabsch; others wait at barrier ----
      if (w == 0) {
        if (lane == 0) {
          while (__hip_atomic_load(cptr, __ATOMIC_RELAXED, __HIP_MEMORY_SCOPE_AGENT)
                 < (unsigned)ARRIVALS)
            __builtin_amdgcn_s_sleep(1);
        }
        // wave reconverged; parallel-issue reduce (independent regs, 1 RTT)
        float vbuf[ROWS_PER_B];
        if (lane < 17) {
          const float* pp = partial + (it & 1) * PART_SZ;
#pragma unroll
          for (int c = 0; c < ROWS_PER_B; ++c)
            vbuf[c] = __hip_atomic_load(pp + (b*ROWS_PER_B + c)*PSTRIDE + lane,
                                        __ATOMIC_RELAXED, __HIP_MEMORY_SCOPE_AGENT);
        } else {
#pragma unroll
          for (int c = 0; c < ROWS_PER_B; ++c) vbuf[c] = 0.f;
        }
        float s = 0.f;
#pragma unroll
        for (int c = 0; c < ROWS_PER_B; ++c) s += vbuf[c];
        float S[17];
#pragma unroll
        for (int i = 0; i < 17; ++i) S[i] = __shfl(s, i);
        float Rn[3][3], tn[3];
        kabsch_from_sums(S, Rn, tn);
        if (lane == 0) {
          for (int i = 0; i < 3; ++i)
            for (int j = 0; j < 3; ++j) Rsh[i*3+j] = Rn[i][j];
          for (int i = 0; i < 3; ++i) Rsh[9+i] = tn[i];
          Rsh[12] = S[16] * (1.f / (float)M_);
        }
      }
      __syncthreads();
      // ---- all threads pick up the update ----
#pragma unroll
      for (int i = 0; i < 3; ++i) {
#pragma unroll
        for (int j = 0; j < 3; ++j) Rc[i][j] = Rsh[i*3+j];
        tc[i] = Rsh[9+i];
      }
      mse = Rsh[12];
      if (mse < MSE_THR) done = true;
      // LDS reuse next iteration ordered by the barriers above
    }
  }

  // ---- emit outputs (one writer per batch) ----
  if (sub == 0 && tid == 0) {
#pragma unroll
    for (int i = 0; i < 3; ++i)
#pragma unroll
      for (int j = 0; j < 3; ++j) out[b*9 + i*3 + j] = Rc[i][j];
#pragma unroll
    for (int i = 0; i < 3; ++i) out[144 + b*3 + i] = tc[i];
    out[192 + b] = mse;
  }
}

extern "C" void kernel_launch(void* const* d_in, const int* in_sizes, int n_in,
                              void* d_out, int out_size, void* d_ws, size_t ws_size,
                              hipStream_t stream) {
  const float* src  = (const float*)d_in[0];
  const float* dest = (const float*)d_in[1];
  float* out = (float*)d_out;
  float* ws = (float*)d_ws;

  // zero the (poisoned) arrival counters first
  hipLaunchKernelGGL(icp_init, dim3((B_*ITERS*CNT_STRIDE + 255)/256), dim3(256), 0,
                     stream, (unsigned*)ws);

  // REGULAR launch: grid (256x1024 = 262k threads) is <= 50% of device thread
  // capacity with __launch_bounds__(1024,2), so all blocks are co-resident and
  // the arrival barrier is safe without the cooperative-launch overhead.
  hipLaunchKernelGGL(icp_fused, dim3(256), dim3(THREADS), 0, stream,
                     src, dest, ws, out);
}